// Round 1
// baseline (1163.126 us; speedup 1.0000x reference)
//
#include <hip/hip_runtime.h>
#include <math.h>

// ---------------------------------------------------------------------------
// LSGC: B=32, C=128, H=W=64. N_pixels per channel = 32*64*64 = 131072.
// Pipeline:
//   1) stencil: fmax = x - min over {self, h±s, w±s : s in 2,4,8,16,32} (circular)
//   2) GEMM1a: y_in  = w_in  @ x     (+ per-channel sum/sumsq)
//      GEMM1b: y_df  = w_diff@ fmax  (+ per-channel sum/sumsq)
//   3) finalize1: a_in,d_in,a_df ; w_eff[o,c] = w_mr[o,c]*a_{in|df}[c]
//      (conv biases & BN additive consts cancel inside the next BN)
//   4) GEMM2: h_pre = w_eff @ [y_in ; y_df]  (+ sum/sumsq)
//   5) finalize2: a_m, d_m
//   6) epilogue: out = a_in*y_in + d_in + gelu(a_m*h_pre + d_m)
// ---------------------------------------------------------------------------

#define INV_NPIX (1.0f / 131072.0f)
#define EPS 1e-5f

// --------------------------- stencil ---------------------------------------
__global__ __launch_bounds__(256) void stencil_kernel(
    const float* __restrict__ x, float* __restrict__ out) {
  __shared__ float p[4096];
  const size_t base = (size_t)blockIdx.x * 4096;
  for (int i = threadIdx.x; i < 4096; i += 256) p[i] = x[base + i];
  __syncthreads();
  for (int i = threadIdx.x; i < 4096; i += 256) {
    const int hbase = i & ~63;
    const int w = i & 63;
    const float v = p[i];
    float mn = v;
#pragma unroll
    for (int sidx = 0; sidx < 5; ++sidx) {
      const int s = 2 << sidx;  // 2,4,8,16,32
      mn = fminf(mn, p[hbase | ((w + s) & 63)]);
      mn = fminf(mn, p[hbase | ((w + 64 - s) & 63)]);
      mn = fminf(mn, p[(i + (s << 6)) & 4095]);
      mn = fminf(mn, p[(i + 4096 - (s << 6)) & 4095]);
    }
    out[base + i] = v - mn;
  }
}

// --------------------------- GEMM + BN stats --------------------------------
// C[m,n] = sum_k A[m,k] * B[k,n]; A row-major [128 x K].
// B logical [K x 131072]: row k of batch b lives at
//   (k<128 ? B0 : B1) + (b*128 + (k&127))*4096 + hw
// Tile: 64(M) x 64(N), K-chunk 32. 256 threads, 4x4 per thread.
template <int K>
__global__ __launch_bounds__(256) void gemm_bn(
    const float* __restrict__ A, const float* __restrict__ B0,
    const float* __restrict__ B1, float* __restrict__ out,
    float* __restrict__ sumv, float* __restrict__ sumq) {
  __shared__ float As[32][68];  // [k][m]
  __shared__ float Bs[32][68];  // [k][n]

  const int tid = threadIdx.x;
  const int b = blockIdx.x >> 6;
  const int hw0 = (blockIdx.x & 63) << 6;
  const int m0 = blockIdx.y << 6;
  const int tx = tid & 15, ty = tid >> 4;

  float acc[4][4] = {{0.f, 0.f, 0.f, 0.f},
                     {0.f, 0.f, 0.f, 0.f},
                     {0.f, 0.f, 0.f, 0.f},
                     {0.f, 0.f, 0.f, 0.f}};

  for (int k0 = 0; k0 < K; k0 += 32) {
    // A tile: 64 m x 32 k, vectorized along k
    {
      const int tm = tid >> 3;
      const int tk = (tid & 7) << 2;
#pragma unroll
      for (int r = 0; r < 2; ++r) {
        const int m = tm + (r << 5);
        const float4 v =
            *(const float4*)&A[(size_t)(m0 + m) * K + k0 + tk];
        As[tk + 0][m] = v.x;
        As[tk + 1][m] = v.y;
        As[tk + 2][m] = v.z;
        As[tk + 3][m] = v.w;
      }
    }
    // B tile: 32 k x 64 n, vectorized along n
    {
      const int tk = tid >> 4;
      const int tn = (tid & 15) << 2;
      const float* src = (K == 256 && k0 >= 128) ? B1 : B0;
      const int kb = k0 & 127;
#pragma unroll
      for (int r = 0; r < 2; ++r) {
        const int k = kb + tk + (r << 4);
        const float4 v = *(const float4*)&src[((size_t)b * 128 + k) * 4096 +
                                              hw0 + tn];
        *(float4*)&Bs[tk + (r << 4)][tn] = v;
      }
    }
    __syncthreads();
#pragma unroll
    for (int kk = 0; kk < 32; ++kk) {
      float a[4], bv[4];
      *(float4*)a = *(const float4*)&As[kk][ty << 2];
      *(float4*)bv = *(const float4*)&Bs[kk][tx << 2];
#pragma unroll
      for (int i = 0; i < 4; ++i)
#pragma unroll
        for (int j = 0; j < 4; ++j)
          acc[i][j] = fmaf(a[i], bv[j], acc[i][j]);
    }
    __syncthreads();
  }

  // store + per-channel stats
  float psum[4], psq[4];
#pragma unroll
  for (int i = 0; i < 4; ++i) {
    const int m = m0 + (ty << 2) + i;
    float4 v = make_float4(acc[i][0], acc[i][1], acc[i][2], acc[i][3]);
    *(float4*)&out[((size_t)b * 128 + m) * 4096 + hw0 + (tx << 2)] = v;
    psum[i] = v.x + v.y + v.z + v.w;
    psq[i] = v.x * v.x + v.y * v.y + v.z * v.z + v.w * v.w;
  }
#pragma unroll
  for (int off = 1; off < 16; off <<= 1) {
#pragma unroll
    for (int i = 0; i < 4; ++i) {
      psum[i] += __shfl_xor(psum[i], off);
      psq[i] += __shfl_xor(psq[i], off);
    }
  }
  if (tx == 0) {
#pragma unroll
    for (int i = 0; i < 4; ++i) {
      const int m = m0 + (ty << 2) + i;
      atomicAdd(&sumv[m], psum[i]);
      atomicAdd(&sumq[m], psq[i]);
    }
  }
}

// --------------------------- finalize kernels -------------------------------
__global__ __launch_bounds__(256) void finalize1_kernel(
    const float* __restrict__ s_in, const float* __restrict__ q_in,
    const float* __restrict__ s_df, const float* __restrict__ q_df,
    const float* __restrict__ g_ibn, const float* __restrict__ be_ibn,
    const float* __restrict__ g_bn, const float* __restrict__ w_mr,
    float* __restrict__ a_in, float* __restrict__ d_in,
    float* __restrict__ a_df, float* __restrict__ w_eff) {
  __shared__ float sa[256];
  const int t = threadIdx.x;
  if (t < 128) {
    const float mu = s_in[t] * INV_NPIX;
    const float var = fmaxf(q_in[t] * INV_NPIX - mu * mu, 0.f);
    const float a = g_ibn[t] * rsqrtf(var + EPS);
    a_in[t] = a;
    d_in[t] = be_ibn[t] - mu * a;
    sa[t] = a;
  } else {
    const int c = t - 128;
    const float mu = s_df[c] * INV_NPIX;
    const float var = fmaxf(q_df[c] * INV_NPIX - mu * mu, 0.f);
    const float a = g_bn[c] * rsqrtf(var + EPS);
    a_df[c] = a;
    sa[t] = a;
  }
  __syncthreads();
  for (int idx = t; idx < 128 * 256; idx += 256)
    w_eff[idx] = w_mr[idx] * sa[idx & 255];
}

__global__ __launch_bounds__(128) void finalize2_kernel(
    const float* __restrict__ s_h, const float* __restrict__ q_h,
    const float* __restrict__ g_mbn, const float* __restrict__ be_mbn,
    float* __restrict__ a_m, float* __restrict__ d_m) {
  const int t = threadIdx.x;
  const float mu = s_h[t] * INV_NPIX;
  const float var = fmaxf(q_h[t] * INV_NPIX - mu * mu, 0.f);
  const float a = g_mbn[t] * rsqrtf(var + EPS);
  a_m[t] = a;
  d_m[t] = be_mbn[t] - mu * a;
}

// --------------------------- epilogue ---------------------------------------
__device__ __forceinline__ float gelu_exact(float z) {
  return 0.5f * z * (1.0f + erff(z * 0.70710678118654752f));
}

__global__ __launch_bounds__(256) void epilogue_kernel(
    const float* __restrict__ y_in, const float* __restrict__ h_pre,
    const float* __restrict__ a_in, const float* __restrict__ d_in,
    const float* __restrict__ a_m, const float* __restrict__ d_m,
    float* __restrict__ out) {
  const size_t i = (size_t)blockIdx.x * 256 + threadIdx.x;  // float4 index
  const int c = (int)((i >> 10) & 127);
  const float4 y = ((const float4*)y_in)[i];
  const float4 h = ((const float4*)h_pre)[i];
  const float ai = a_in[c], di = d_in[c], am = a_m[c], dm = d_m[c];
  float4 o;
  o.x = fmaf(ai, y.x, di) + gelu_exact(fmaf(am, h.x, dm));
  o.y = fmaf(ai, y.y, di) + gelu_exact(fmaf(am, h.y, dm));
  o.z = fmaf(ai, y.z, di) + gelu_exact(fmaf(am, h.z, dm));
  o.w = fmaf(ai, y.w, di) + gelu_exact(fmaf(am, h.w, dm));
  ((float4*)out)[i] = o;
}

// --------------------------- launch -----------------------------------------
extern "C" void kernel_launch(void* const* d_in, const int* in_sizes, int n_in,
                              void* d_out, int out_size, void* d_ws,
                              size_t ws_size, hipStream_t stream) {
  const float* x = (const float*)d_in[0];
  const float* w_diff = (const float*)d_in[1];
  const float* g_bn = (const float*)d_in[3];
  const float* w_in = (const float*)d_in[5];
  const float* g_ibn = (const float*)d_in[7];
  const float* be_ibn = (const float*)d_in[8];
  const float* w_mr = (const float*)d_in[9];
  const float* g_mbn = (const float*)d_in[11];
  const float* be_mbn = (const float*)d_in[12];
  float* out = (float*)d_out;

  const size_t NB = (size_t)16777216;  // 32*128*64*64
  float* ws = (float*)d_ws;
  float* buf0 = ws;            // fmax, then h_pre
  float* buf1 = ws + NB;       // y_in
  float* buf2 = ws + 2 * NB;   // y_diff
  float* st = ws + 3 * NB;
  float* s_in = st, *q_in = st + 128;
  float* s_df = st + 256, *q_df = st + 384;
  float* s_h = st + 512, *q_h = st + 640;
  float* a_in = st + 768, *dinc = st + 896;
  float* a_df = st + 1024;
  float* a_m = st + 1152, *d_m = st + 1280;
  float* w_eff = st + 1408;  // 128*256

  hipMemsetAsync(st, 0, 768 * sizeof(float), stream);
  stencil_kernel<<<4096, 256, 0, stream>>>(x, buf0);
  gemm_bn<128><<<dim3(2048, 2), 256, 0, stream>>>(w_in, x, nullptr, buf1,
                                                  s_in, q_in);
  gemm_bn<128><<<dim3(2048, 2), 256, 0, stream>>>(w_diff, buf0, nullptr, buf2,
                                                  s_df, q_df);
  finalize1_kernel<<<1, 256, 0, stream>>>(s_in, q_in, s_df, q_df, g_ibn,
                                          be_ibn, g_bn, w_mr, a_in, dinc,
                                          a_df, w_eff);
  gemm_bn<256><<<dim3(2048, 2), 256, 0, stream>>>(w_eff, buf1, buf2, buf0,
                                                  s_h, q_h);
  finalize2_kernel<<<1, 128, 0, stream>>>(s_h, q_h, g_mbn, be_mbn, a_m, d_m);
  epilogue_kernel<<<16384, 256, 0, stream>>>(buf1, buf0, a_in, dinc, a_m, d_m,
                                             out);
}

// Round 2
// 840.957 us; speedup vs baseline: 1.3831x; 1.3831x over previous
//
#include <hip/hip_runtime.h>
#include <math.h>

// ---------------------------------------------------------------------------
// LSGC: B=32, C=128, H=W=64. N_pixels = 32*64*64 = 131072.
//   1) stencil: fmax = x - min over {self, h±s, w±s : s in 2,4,8,16,32} (circ)
//   2) GEMM1a: y_in = w_in @ x ; GEMM1b: y_df = w_diff @ fmax  (+BN stats)
//   3) finalize1: BN scales; w_eff = w_mr * col-scale (additive terms cancel)
//   4) GEMM2: h_pre = w_eff @ [y_in ; y_df] (+BN stats)
//   5) finalize2 ; 6) epilogue: out = a_in*y_in + d_in + gelu(a_m*h + d_m)
// GEMMs: MFMA bf16 16x16x32 with hi/lo split (3 mfma) for fp32-grade accuracy.
// ---------------------------------------------------------------------------

#define INV_NPIX (1.0f / 131072.0f)
#define EPS 1e-5f
#define KP 66  // LDS dword stride per k-row (64 + 2 pad: conflict-free)

typedef __attribute__((ext_vector_type(8))) short s16x8;
typedef __attribute__((ext_vector_type(4))) float f32x4;

__device__ __forceinline__ uint32_t bf16_rne(float v) {
  uint32_t x = __float_as_uint(v);
  return (x + 0x7fffu + ((x >> 16) & 1u)) >> 16;
}
// pack (hi bf16) | (lo bf16 << 16), v ~= hi + lo
__device__ __forceinline__ uint32_t pack_hl(float v) {
  uint32_t h = bf16_rne(v);
  float lo = v - __uint_as_float(h << 16);
  return h | (bf16_rne(lo) << 16);
}

// --------------------------- stencil ---------------------------------------
__global__ __launch_bounds__(256) void stencil_kernel(
    const float* __restrict__ x, float* __restrict__ out) {
  __shared__ float p[4096];
  const size_t base = (size_t)blockIdx.x * 4096;
  for (int i = threadIdx.x; i < 4096; i += 256) p[i] = x[base + i];
  __syncthreads();
  for (int i = threadIdx.x; i < 4096; i += 256) {
    const int hbase = i & ~63;
    const int w = i & 63;
    const float v = p[i];
    float mn = v;
#pragma unroll
    for (int sidx = 0; sidx < 5; ++sidx) {
      const int s = 2 << sidx;  // 2,4,8,16,32
      mn = fminf(mn, p[hbase | ((w + s) & 63)]);
      mn = fminf(mn, p[hbase | ((w + 64 - s) & 63)]);
      mn = fminf(mn, p[(i + (s << 6)) & 4095]);
      mn = fminf(mn, p[(i + 4096 - (s << 6)) & 4095]);
    }
    out[base + i] = v - mn;
  }
}

// --------------------------- weight prep (frag order, hi/lo) ---------------
// aH/aL[e], e = ((kc*8 + mt)*64 + lane)*8 + j  ->  A[m][k],
//   m = mt*16 + (lane&15), k = kc*32 + (lane>>4)*8 + j   (Kdim = 128)
__global__ __launch_bounds__(256) void prep_weights(
    const float* __restrict__ w, unsigned short* __restrict__ aH,
    unsigned short* __restrict__ aL) {
  const int e = blockIdx.x * 256 + threadIdx.x;  // 64 blocks -> 16384
  const int j = e & 7, l = (e >> 3) & 63, mt = (e >> 9) & 7, kc = e >> 12;
  const int m = mt * 16 + (l & 15);
  const int k = kc * 32 + ((l >> 4) << 3) + j;
  const uint32_t p = pack_hl(w[m * 128 + k]);
  aH[e] = (unsigned short)(p & 0xffffu);
  aL[e] = (unsigned short)(p >> 16);
}

// --------------------------- MFMA GEMM + BN stats ---------------------------
// out[m,n] = sum_k A[m,k]*B[k,n]; M=128, N=131072.
// B row k of batch b at (k<128 ? B0 : B1) + (b*128 + (k&127))*4096 + hw.
// Block: 256 thr (4 waves), tile M=128 x N=64, K-chunk 32. Grid 2048.
template <int K>
__global__ __launch_bounds__(256) void gemm_mfma(
    const unsigned short* __restrict__ AH, const unsigned short* __restrict__ AL,
    const float* __restrict__ B0, const float* __restrict__ B1,
    float* __restrict__ out, float* __restrict__ sumv,
    float* __restrict__ sumq) {
  __shared__ uint32_t Bs[32 * KP];  // interleaved (hi|lo<<16) per (k,n)

  const int tid = threadIdx.x;
  const int lane = tid & 63;
  const int wave = tid >> 6;
  const int b = blockIdx.x >> 6;
  const int hw0 = (blockIdx.x & 63) << 6;
  const int sn4 = tid & 15;  // staging: float4 column
  const int sk = tid >> 4;   // staging: k-row (0..15), +16 second slot
  const int q = lane >> 4;
  const int ln = lane & 15;

  f32x4 acc[2][4];
#pragma unroll
  for (int i = 0; i < 2; ++i)
#pragma unroll
    for (int j = 0; j < 4; ++j) acc[i][j] = (f32x4)(0.0f);

#pragma unroll
  for (int kc = 0; kc < K / 32; ++kc) {
    const float* src = (K == 256 && kc >= 4) ? B1 : B0;
    const int kbase = (K == 256 && kc >= 4) ? (kc - 4) * 32 : kc * 32;
    // ---- stage B chunk: fp32 -> hi/lo interleaved dwords in LDS ----
#pragma unroll
    for (int s = 0; s < 2; ++s) {
      const int kr = sk + s * 16;
      const float4 v = *(const float4*)&src[((size_t)b * 128 + kbase + kr) *
                                                4096 + hw0 + (sn4 << 2)];
      uint2 d01, d23;
      d01.x = pack_hl(v.x);
      d01.y = pack_hl(v.y);
      d23.x = pack_hl(v.z);
      d23.y = pack_hl(v.w);
      *(uint2*)&Bs[kr * KP + (sn4 << 2)] = d01;
      *(uint2*)&Bs[kr * KP + (sn4 << 2) + 2] = d23;
    }
    __syncthreads();
    // ---- A frags (global, L2-resident, frag-ordered) ----
    s16x8 ah[2], al[2];
#pragma unroll
    for (int mt2 = 0; mt2 < 2; ++mt2) {
      const size_t off =
          ((size_t)((kc * 8 + wave * 2 + mt2) * 64 + lane)) << 3;
      ah[mt2] = *(const s16x8*)(AH + off);
      al[mt2] = *(const s16x8*)(AL + off);
    }
    // ---- compute ----
#pragma unroll
    for (int nt = 0; nt < 4; ++nt) {
      uint32_t dj[8];
#pragma unroll
      for (int j = 0; j < 8; ++j)
        dj[j] = Bs[(q * 8 + j) * KP + nt * 16 + ln];
      union { uint32_t u[4]; s16x8 s; } bh, bl;
#pragma unroll
      for (int jj = 0; jj < 4; ++jj) {
        bh.u[jj] = __builtin_amdgcn_perm(dj[2 * jj + 1], dj[2 * jj], 0x05040100u);
        bl.u[jj] = __builtin_amdgcn_perm(dj[2 * jj + 1], dj[2 * jj], 0x07060302u);
      }
#pragma unroll
      for (int mt2 = 0; mt2 < 2; ++mt2) {
        acc[mt2][nt] = __builtin_amdgcn_mfma_f32_16x16x32_bf16(
            ah[mt2], bh.s, acc[mt2][nt], 0, 0, 0);
        acc[mt2][nt] = __builtin_amdgcn_mfma_f32_16x16x32_bf16(
            ah[mt2], bl.s, acc[mt2][nt], 0, 0, 0);
        acc[mt2][nt] = __builtin_amdgcn_mfma_f32_16x16x32_bf16(
            al[mt2], bh.s, acc[mt2][nt], 0, 0, 0);
      }
    }
    __syncthreads();
  }

  // ---- store + per-channel stats ----
#pragma unroll
  for (int mt2 = 0; mt2 < 2; ++mt2) {
    float sa[4] = {0.f, 0.f, 0.f, 0.f};
    float sq[4] = {0.f, 0.f, 0.f, 0.f};
#pragma unroll
    for (int nt = 0; nt < 4; ++nt) {
#pragma unroll
      for (int r = 0; r < 4; ++r) {
        const float v = acc[mt2][nt][r];
        const int m = (wave * 2 + mt2) * 16 + q * 4 + r;
        out[((size_t)b * 128 + m) * 4096 + hw0 + nt * 16 + ln] = v;
        sa[r] += v;
        sq[r] += v * v;
      }
    }
#pragma unroll
    for (int off = 1; off < 16; off <<= 1) {
#pragma unroll
      for (int r = 0; r < 4; ++r) {
        sa[r] += __shfl_xor(sa[r], off);
        sq[r] += __shfl_xor(sq[r], off);
      }
    }
    if (ln == 0) {
#pragma unroll
      for (int r = 0; r < 4; ++r) {
        const int m = (wave * 2 + mt2) * 16 + q * 4 + r;
        atomicAdd(&sumv[m], sa[r]);
        atomicAdd(&sumq[m], sq[r]);
      }
    }
  }
}

// --------------------------- finalize kernels -------------------------------
__global__ __launch_bounds__(256) void finalize1_kernel(
    const float* __restrict__ s_in, const float* __restrict__ q_in,
    const float* __restrict__ s_df, const float* __restrict__ q_df,
    const float* __restrict__ g_ibn, const float* __restrict__ be_ibn,
    const float* __restrict__ g_bn, const float* __restrict__ w_mr,
    float* __restrict__ a_in, float* __restrict__ d_in,
    unsigned short* __restrict__ wEffH, unsigned short* __restrict__ wEffL) {
  __shared__ float sa[256];
  const int t = threadIdx.x;
  if (t < 128) {
    const float mu = s_in[t] * INV_NPIX;
    const float var = fmaxf(q_in[t] * INV_NPIX - mu * mu, 0.f);
    const float a = g_ibn[t] * rsqrtf(var + EPS);
    a_in[t] = a;
    d_in[t] = be_ibn[t] - mu * a;
    sa[t] = a;
  } else {
    const int c = t - 128;
    const float mu = s_df[c] * INV_NPIX;
    const float var = fmaxf(q_df[c] * INV_NPIX - mu * mu, 0.f);
    sa[t] = g_bn[c] * rsqrtf(var + EPS);
  }
  __syncthreads();
  // frag-ordered hi/lo of w_eff[m][k] = w_mr[m][k]*sa[k], Kdim=256
  for (int e = t; e < 32768; e += 256) {
    const int j = e & 7, l = (e >> 3) & 63, mt = (e >> 9) & 7, kc = e >> 12;
    const int m = mt * 16 + (l & 15);
    const int k = kc * 32 + ((l >> 4) << 3) + j;
    const uint32_t p = pack_hl(w_mr[m * 256 + k] * sa[k]);
    wEffH[e] = (unsigned short)(p & 0xffffu);
    wEffL[e] = (unsigned short)(p >> 16);
  }
}

__global__ __launch_bounds__(128) void finalize2_kernel(
    const float* __restrict__ s_h, const float* __restrict__ q_h,
    const float* __restrict__ g_mbn, const float* __restrict__ be_mbn,
    float* __restrict__ a_m, float* __restrict__ d_m) {
  const int t = threadIdx.x;
  const float mu = s_h[t] * INV_NPIX;
  const float var = fmaxf(q_h[t] * INV_NPIX - mu * mu, 0.f);
  const float a = g_mbn[t] * rsqrtf(var + EPS);
  a_m[t] = a;
  d_m[t] = be_mbn[t] - mu * a;
}

// --------------------------- epilogue ---------------------------------------
__device__ __forceinline__ float gelu_exact(float z) {
  return 0.5f * z * (1.0f + erff(z * 0.70710678118654752f));
}

__global__ __launch_bounds__(256) void epilogue_kernel(
    const float* __restrict__ y_in, const float* __restrict__ h_pre,
    const float* __restrict__ a_in, const float* __restrict__ d_in,
    const float* __restrict__ a_m, const float* __restrict__ d_m,
    float* __restrict__ out) {
  const size_t i = (size_t)blockIdx.x * 256 + threadIdx.x;  // float4 index
  const int c = (int)((i >> 10) & 127);
  const float4 y = ((const float4*)y_in)[i];
  const float4 h = ((const float4*)h_pre)[i];
  const float ai = a_in[c], di = d_in[c], am = a_m[c], dm = d_m[c];
  float4 o;
  o.x = fmaf(ai, y.x, di) + gelu_exact(fmaf(am, h.x, dm));
  o.y = fmaf(ai, y.y, di) + gelu_exact(fmaf(am, h.y, dm));
  o.z = fmaf(ai, y.z, di) + gelu_exact(fmaf(am, h.z, dm));
  o.w = fmaf(ai, y.w, di) + gelu_exact(fmaf(am, h.w, dm));
  ((float4*)out)[i] = o;
}

// --------------------------- launch -----------------------------------------
extern "C" void kernel_launch(void* const* d_in, const int* in_sizes, int n_in,
                              void* d_out, int out_size, void* d_ws,
                              size_t ws_size, hipStream_t stream) {
  const float* x = (const float*)d_in[0];
  const float* w_diff = (const float*)d_in[1];
  const float* g_bn = (const float*)d_in[3];
  const float* w_in = (const float*)d_in[5];
  const float* g_ibn = (const float*)d_in[7];
  const float* be_ibn = (const float*)d_in[8];
  const float* w_mr = (const float*)d_in[9];
  const float* g_mbn = (const float*)d_in[11];
  const float* be_mbn = (const float*)d_in[12];
  float* out = (float*)d_out;

  const size_t NB = (size_t)16777216;  // 32*128*64*64
  float* ws = (float*)d_ws;
  float* buf0 = ws;           // fmax, then h_pre
  float* buf1 = ws + NB;      // y_in
  float* buf2 = ws + 2 * NB;  // y_diff
  float* st = ws + 3 * NB;
  float* s_in = st, *q_in = st + 128;
  float* s_df = st + 256, *q_df = st + 384;
  float* s_h = st + 512, *q_h = st + 640;
  float* a_in = st + 768, *dinc = st + 896;
  float* a_m = st + 1024, *d_m = st + 1152;
  unsigned short* fr = (unsigned short*)(st + 2048);
  unsigned short* wInH = fr;             // 16384 each
  unsigned short* wInL = fr + 16384;
  unsigned short* wDfH = fr + 32768;
  unsigned short* wDfL = fr + 49152;
  unsigned short* wEffH = fr + 65536;    // 32768 each
  unsigned short* wEffL = fr + 98304;

  hipMemsetAsync(st, 0, 768 * sizeof(float), stream);
  prep_weights<<<64, 256, 0, stream>>>(w_in, wInH, wInL);
  prep_weights<<<64, 256, 0, stream>>>(w_diff, wDfH, wDfL);
  stencil_kernel<<<4096, 256, 0, stream>>>(x, buf0);
  gemm_mfma<128><<<2048, 256, 0, stream>>>(wInH, wInL, x, nullptr, buf1,
                                           s_in, q_in);
  gemm_mfma<128><<<2048, 256, 0, stream>>>(wDfH, wDfL, buf0, nullptr, buf2,
                                           s_df, q_df);
  finalize1_kernel<<<1, 256, 0, stream>>>(s_in, q_in, s_df, q_df, g_ibn,
                                          be_ibn, g_bn, w_mr, a_in, dinc,
                                          wEffH, wEffL);
  gemm_mfma<256><<<2048, 256, 0, stream>>>(wEffH, wEffL, buf1, buf2, buf0,
                                           s_h, q_h);
  finalize2_kernel<<<1, 128, 0, stream>>>(s_h, q_h, g_mbn, be_mbn, a_m, d_m);
  epilogue_kernel<<<16384, 256, 0, stream>>>(buf1, buf0, a_in, dinc, a_m, d_m,
                                             out);
}

// Round 3
// 316.540 us; speedup vs baseline: 3.6745x; 2.6567x over previous
//
#include <hip/hip_runtime.h>
#include <math.h>

// ---------------------------------------------------------------------------
// LSGC: B=32, C=128, H=W=64. N_pixels = 32*64*64 = 131072.
//   1) stencil: fmax = x - min over {self, h±s, w±s : s in 2,4,8,16,32} (circ)
//   2) GEMM1a: y_in = w_in @ x ; GEMM1b: y_df = w_diff @ fmax  (+BN stats)
//   3) finalize1: BN scales; w_eff = w_mr * col-scale (additive terms cancel)
//   4) GEMM2: h_pre = w_eff @ [y_in ; y_df] (+BN stats)
//   5) finalize2 ; 6) epilogue: out = a_in*y_in + d_in + gelu(a_m*h + d_m)
// GEMMs: MFMA bf16 16x16x32 hi/lo split (3 mfma) for fp32-grade accuracy.
// BN stats: 32-way-spread atomics (blockIdx&31) -> reduce in finalize.
// K-loop: register-prefetch software pipeline (B chunk k+1 loads overlap
// compute of chunk k; A frags issued before B prefetch so mfma's vmcnt wait
// doesn't drain the prefetch).
// ---------------------------------------------------------------------------

#define INV_NPIX (1.0f / 131072.0f)
#define EPS 1e-5f
#define KP 66  // LDS dword stride per k-row (64 + 2 pad: conflict-free)

typedef __attribute__((ext_vector_type(8))) short s16x8;
typedef __attribute__((ext_vector_type(4))) float f32x4;

__device__ __forceinline__ uint32_t bf16_rne(float v) {
  uint32_t x = __float_as_uint(v);
  return (x + 0x7fffu + ((x >> 16) & 1u)) >> 16;
}
// pack (hi bf16) | (lo bf16 << 16), v ~= hi + lo
__device__ __forceinline__ uint32_t pack_hl(float v) {
  uint32_t h = bf16_rne(v);
  float lo = v - __uint_as_float(h << 16);
  return h | (bf16_rne(lo) << 16);
}

// --------------------------- stencil ---------------------------------------
__global__ __launch_bounds__(256) void stencil_kernel(
    const float* __restrict__ x, float* __restrict__ out) {
  __shared__ float p[4096];
  const size_t base = (size_t)blockIdx.x * 4096;
  for (int i = threadIdx.x; i < 4096; i += 256) p[i] = x[base + i];
  __syncthreads();
  for (int i = threadIdx.x; i < 4096; i += 256) {
    const int hbase = i & ~63;
    const int w = i & 63;
    const float v = p[i];
    float mn = v;
#pragma unroll
    for (int sidx = 0; sidx < 5; ++sidx) {
      const int s = 2 << sidx;  // 2,4,8,16,32
      mn = fminf(mn, p[hbase | ((w + s) & 63)]);
      mn = fminf(mn, p[hbase | ((w + 64 - s) & 63)]);
      mn = fminf(mn, p[(i + (s << 6)) & 4095]);
      mn = fminf(mn, p[(i + 4096 - (s << 6)) & 4095]);
    }
    out[base + i] = v - mn;
  }
}

// --------------------------- weight prep (frag order, hi/lo) ---------------
// aH/aL[e], e = ((kc*8 + mt)*64 + lane)*8 + j  ->  A[m][k],
//   m = mt*16 + (lane&15), k = kc*32 + (lane>>4)*8 + j   (Kdim = 128)
// blocks 0..63: w_in, blocks 64..127: w_diff
__global__ __launch_bounds__(256) void prep_weights(
    const float* __restrict__ w_in, const float* __restrict__ w_diff,
    unsigned short* __restrict__ wInH, unsigned short* __restrict__ wInL,
    unsigned short* __restrict__ wDfH, unsigned short* __restrict__ wDfL) {
  const int blk = blockIdx.x;
  const float* w = (blk < 64) ? w_in : w_diff;
  unsigned short* aH = (blk < 64) ? wInH : wDfH;
  unsigned short* aL = (blk < 64) ? wInL : wDfL;
  const int e = (blk & 63) * 256 + threadIdx.x;  // 16384 total
  const int j = e & 7, l = (e >> 3) & 63, mt = (e >> 9) & 7, kc = e >> 12;
  const int m = mt * 16 + (l & 15);
  const int k = kc * 32 + ((l >> 4) << 3) + j;
  const uint32_t p = pack_hl(w[m * 128 + k]);
  aH[e] = (unsigned short)(p & 0xffffu);
  aL[e] = (unsigned short)(p >> 16);
}

// --------------------------- MFMA GEMM + BN stats ---------------------------
// out[m,n] = sum_k A[m,k]*B[k,n]; M=128, N=131072.
// B row k of batch b at (k<128 ? B0 : B1) + (b*128 + (k&127))*4096 + hw.
// Block: 256 thr (4 waves), tile M=128 x N=64, K-chunk 32. Grid 2048.
// sumv/sumq are 32 x 128 spread accumulators.
template <int K>
__global__ __launch_bounds__(256) void gemm_mfma(
    const unsigned short* __restrict__ AH, const unsigned short* __restrict__ AL,
    const float* __restrict__ B0, const float* __restrict__ B1,
    float* __restrict__ out, float* __restrict__ sumv,
    float* __restrict__ sumq) {
  __shared__ uint32_t Bs[32 * KP];  // interleaved (hi|lo<<16) per (k,n)

  const int tid = threadIdx.x;
  const int lane = tid & 63;
  const int wave = tid >> 6;
  const int b = blockIdx.x >> 6;
  const int hw0 = (blockIdx.x & 63) << 6;
  const int sn4 = tid & 15;  // staging: float4 column
  const int sk = tid >> 4;   // staging: k-row (0..15), +16 second slot
  const int q = lane >> 4;
  const int ln = lane & 15;
  const int NC = K / 32;

  f32x4 acc[2][4];
#pragma unroll
  for (int i = 0; i < 2; ++i)
#pragma unroll
    for (int j = 0; j < 4; ++j) acc[i][j] = (f32x4)(0.0f);

  // prologue: load chunk 0 of B into registers
  float4 vreg[2];
#pragma unroll
  for (int s = 0; s < 2; ++s) {
    const int kr = sk + s * 16;
    vreg[s] =
        *(const float4*)&B0[((size_t)b * 128 + kr) * 4096 + hw0 + (sn4 << 2)];
  }

#pragma unroll
  for (int kc = 0; kc < NC; ++kc) {
    // ---- pack current chunk into LDS ----
#pragma unroll
    for (int s = 0; s < 2; ++s) {
      const int kr = sk + s * 16;
      uint2 d01, d23;
      d01.x = pack_hl(vreg[s].x);
      d01.y = pack_hl(vreg[s].y);
      d23.x = pack_hl(vreg[s].z);
      d23.y = pack_hl(vreg[s].w);
      *(uint2*)&Bs[kr * KP + (sn4 << 2)] = d01;
      *(uint2*)&Bs[kr * KP + (sn4 << 2) + 2] = d23;
    }
    __syncthreads();

    // ---- A frags for this chunk (L2-resident) -- issued BEFORE B prefetch
    s16x8 ah[2], al[2];
#pragma unroll
    for (int mt2 = 0; mt2 < 2; ++mt2) {
      const size_t off =
          ((size_t)((kc * 8 + wave * 2 + mt2) * 64 + lane)) << 3;
      ah[mt2] = *(const s16x8*)(AH + off);
      al[mt2] = *(const s16x8*)(AL + off);
    }

    // ---- prefetch next B chunk into registers ----
    if (kc + 1 < NC) {
      const float* src = (K == 256 && kc + 1 >= 4) ? B1 : B0;
      const int kbase = (K == 256 && kc + 1 >= 4) ? (kc - 3) * 32
                                                  : (kc + 1) * 32;
#pragma unroll
      for (int s = 0; s < 2; ++s) {
        const int kr = sk + s * 16;
        vreg[s] = *(const float4*)&src[((size_t)b * 128 + kbase + kr) * 4096 +
                                       hw0 + (sn4 << 2)];
      }
    }

    // ---- compute ----
#pragma unroll
    for (int nt = 0; nt < 4; ++nt) {
      uint32_t dj[8];
#pragma unroll
      for (int j = 0; j < 8; ++j)
        dj[j] = Bs[(q * 8 + j) * KP + nt * 16 + ln];
      union { uint32_t u[4]; s16x8 s; } bh, bl;
#pragma unroll
      for (int jj = 0; jj < 4; ++jj) {
        bh.u[jj] = __builtin_amdgcn_perm(dj[2 * jj + 1], dj[2 * jj], 0x05040100u);
        bl.u[jj] = __builtin_amdgcn_perm(dj[2 * jj + 1], dj[2 * jj], 0x07060302u);
      }
#pragma unroll
      for (int mt2 = 0; mt2 < 2; ++mt2) {
        acc[mt2][nt] = __builtin_amdgcn_mfma_f32_16x16x32_bf16(
            ah[mt2], bh.s, acc[mt2][nt], 0, 0, 0);
        acc[mt2][nt] = __builtin_amdgcn_mfma_f32_16x16x32_bf16(
            ah[mt2], bl.s, acc[mt2][nt], 0, 0, 0);
        acc[mt2][nt] = __builtin_amdgcn_mfma_f32_16x16x32_bf16(
            al[mt2], bh.s, acc[mt2][nt], 0, 0, 0);
      }
    }
    __syncthreads();
  }

  // ---- store + per-channel stats (32-way spread atomics) ----
  const int cb = (blockIdx.x & 31) * 128;
#pragma unroll
  for (int mt2 = 0; mt2 < 2; ++mt2) {
    float sa[4] = {0.f, 0.f, 0.f, 0.f};
    float sq[4] = {0.f, 0.f, 0.f, 0.f};
#pragma unroll
    for (int nt = 0; nt < 4; ++nt) {
#pragma unroll
      for (int r = 0; r < 4; ++r) {
        const float v = acc[mt2][nt][r];
        const int m = (wave * 2 + mt2) * 16 + q * 4 + r;
        out[((size_t)b * 128 + m) * 4096 + hw0 + nt * 16 + ln] = v;
        sa[r] += v;
        sq[r] += v * v;
      }
    }
#pragma unroll
    for (int off = 1; off < 16; off <<= 1) {
#pragma unroll
      for (int r = 0; r < 4; ++r) {
        sa[r] += __shfl_xor(sa[r], off);
        sq[r] += __shfl_xor(sq[r], off);
      }
    }
    if (ln == 0) {
#pragma unroll
      for (int r = 0; r < 4; ++r) {
        const int m = (wave * 2 + mt2) * 16 + q * 4 + r;
        atomicAdd(&sumv[cb + m], sa[r]);
        atomicAdd(&sumq[cb + m], sq[r]);
      }
    }
  }
}

// --------------------------- finalize kernels -------------------------------
__global__ __launch_bounds__(256) void finalize1_kernel(
    const float* __restrict__ pSin, const float* __restrict__ pQin,
    const float* __restrict__ pSdf, const float* __restrict__ pQdf,
    const float* __restrict__ g_ibn, const float* __restrict__ be_ibn,
    const float* __restrict__ g_bn, const float* __restrict__ w_mr,
    float* __restrict__ a_in, float* __restrict__ d_in,
    unsigned short* __restrict__ wEffH, unsigned short* __restrict__ wEffL) {
  __shared__ float sa[256];
  const int t = threadIdx.x;
  if (t < 128) {
    float s = 0.f, qq = 0.f;
#pragma unroll
    for (int i = 0; i < 32; ++i) {
      s += pSin[i * 128 + t];
      qq += pQin[i * 128 + t];
    }
    const float mu = s * INV_NPIX;
    const float var = fmaxf(qq * INV_NPIX - mu * mu, 0.f);
    const float a = g_ibn[t] * rsqrtf(var + EPS);
    a_in[t] = a;
    d_in[t] = be_ibn[t] - mu * a;
    sa[t] = a;
  } else {
    const int c = t - 128;
    float s = 0.f, qq = 0.f;
#pragma unroll
    for (int i = 0; i < 32; ++i) {
      s += pSdf[i * 128 + c];
      qq += pQdf[i * 128 + c];
    }
    const float mu = s * INV_NPIX;
    const float var = fmaxf(qq * INV_NPIX - mu * mu, 0.f);
    sa[t] = g_bn[c] * rsqrtf(var + EPS);
  }
  __syncthreads();
  // frag-ordered hi/lo of w_eff[m][k] = w_mr[m][k]*sa[k], Kdim=256
  for (int e = t; e < 32768; e += 256) {
    const int j = e & 7, l = (e >> 3) & 63, mt = (e >> 9) & 7, kc = e >> 12;
    const int m = mt * 16 + (l & 15);
    const int k = kc * 32 + ((l >> 4) << 3) + j;
    const uint32_t p = pack_hl(w_mr[m * 256 + k] * sa[k]);
    wEffH[e] = (unsigned short)(p & 0xffffu);
    wEffL[e] = (unsigned short)(p >> 16);
  }
}

__global__ __launch_bounds__(128) void finalize2_kernel(
    const float* __restrict__ pSh, const float* __restrict__ pQh,
    const float* __restrict__ g_mbn, const float* __restrict__ be_mbn,
    float* __restrict__ a_m, float* __restrict__ d_m) {
  const int t = threadIdx.x;
  float s = 0.f, qq = 0.f;
#pragma unroll
  for (int i = 0; i < 32; ++i) {
    s += pSh[i * 128 + t];
    qq += pQh[i * 128 + t];
  }
  const float mu = s * INV_NPIX;
  const float var = fmaxf(qq * INV_NPIX - mu * mu, 0.f);
  const float a = g_mbn[t] * rsqrtf(var + EPS);
  a_m[t] = a;
  d_m[t] = be_mbn[t] - mu * a;
}

// --------------------------- epilogue ---------------------------------------
__device__ __forceinline__ float gelu_exact(float z) {
  return 0.5f * z * (1.0f + erff(z * 0.70710678118654752f));
}

__global__ __launch_bounds__(256) void epilogue_kernel(
    const float* __restrict__ y_in, const float* __restrict__ h_pre,
    const float* __restrict__ a_in, const float* __restrict__ d_in,
    const float* __restrict__ a_m, const float* __restrict__ d_m,
    float* __restrict__ out) {
  const size_t i = (size_t)blockIdx.x * 256 + threadIdx.x;  // float4 index
  const int c = (int)((i >> 10) & 127);
  const float4 y = ((const float4*)y_in)[i];
  const float4 h = ((const float4*)h_pre)[i];
  const float ai = a_in[c], di = d_in[c], am = a_m[c], dm = d_m[c];
  float4 o;
  o.x = fmaf(ai, y.x, di) + gelu_exact(fmaf(am, h.x, dm));
  o.y = fmaf(ai, y.y, di) + gelu_exact(fmaf(am, h.y, dm));
  o.z = fmaf(ai, y.z, di) + gelu_exact(fmaf(am, h.z, dm));
  o.w = fmaf(ai, y.w, di) + gelu_exact(fmaf(am, h.w, dm));
  ((float4*)out)[i] = o;
}

// --------------------------- launch -----------------------------------------
extern "C" void kernel_launch(void* const* d_in, const int* in_sizes, int n_in,
                              void* d_out, int out_size, void* d_ws,
                              size_t ws_size, hipStream_t stream) {
  const float* x = (const float*)d_in[0];
  const float* w_diff = (const float*)d_in[1];
  const float* g_bn = (const float*)d_in[3];
  const float* w_in = (const float*)d_in[5];
  const float* g_ibn = (const float*)d_in[7];
  const float* be_ibn = (const float*)d_in[8];
  const float* w_mr = (const float*)d_in[9];
  const float* g_mbn = (const float*)d_in[11];
  const float* be_mbn = (const float*)d_in[12];
  float* out = (float*)d_out;

  const size_t NB = (size_t)16777216;  // 32*128*64*64
  float* ws = (float*)d_ws;
  float* buf0 = ws;           // fmax, then h_pre
  float* buf1 = ws + NB;      // y_in
  float* buf2 = ws + 2 * NB;  // y_diff
  float* st = ws + 3 * NB;
  // 32-way spread partial stats (each 32*128 = 4096 floats)
  float* pSin = st, *pQin = st + 4096;
  float* pSdf = st + 8192, *pQdf = st + 12288;
  float* pSh = st + 16384, *pQh = st + 20480;
  float* a_in = st + 24576, *dinc = st + 24704;
  float* a_m = st + 24832, *d_m = st + 24960;
  unsigned short* fr = (unsigned short*)(st + 25088);
  unsigned short* wInH = fr;           // 16384 each
  unsigned short* wInL = fr + 16384;
  unsigned short* wDfH = fr + 32768;
  unsigned short* wDfL = fr + 49152;
  unsigned short* wEffH = fr + 65536;  // 32768 each
  unsigned short* wEffL = fr + 98304;

  hipMemsetAsync(st, 0, 24576 * sizeof(float), stream);
  prep_weights<<<128, 256, 0, stream>>>(w_in, w_diff, wInH, wInL, wDfH, wDfL);
  stencil_kernel<<<4096, 256, 0, stream>>>(x, buf0);
  gemm_mfma<128><<<2048, 256, 0, stream>>>(wInH, wInL, x, nullptr, buf1,
                                           pSin, pQin);
  gemm_mfma<128><<<2048, 256, 0, stream>>>(wDfH, wDfL, buf0, nullptr, buf2,
                                           pSdf, pQdf);
  finalize1_kernel<<<1, 256, 0, stream>>>(pSin, pQin, pSdf, pQdf, g_ibn,
                                          be_ibn, g_bn, w_mr, a_in, dinc,
                                          wEffH, wEffL);
  gemm_mfma<256><<<2048, 256, 0, stream>>>(wEffH, wEffL, buf1, buf2, buf0,
                                           pSh, pQh);
  finalize2_kernel<<<1, 128, 0, stream>>>(pSh, pQh, g_mbn, be_mbn, a_m, d_m);
  epilogue_kernel<<<16384, 256, 0, stream>>>(buf1, buf0, a_in, dinc, a_m, d_m,
                                             out);
}

// Round 4
// 276.586 us; speedup vs baseline: 4.2053x; 1.1445x over previous
//
#include <hip/hip_runtime.h>
#include <math.h>

// ---------------------------------------------------------------------------
// LSGC: B=32, C=128, H=W=64. N_pixels = 32*64*64 = 131072.
//   1) stencil: fmax = x - min over {self, h±s, w±s : s in 2,4,8,16,32} (circ)
//      (same dispatch: weight frag-pack + stats zeroing in extra blocks)
//   2) gemm1 dual: y_in = w_in @ x ; y_df = w_diff @ fmax  (+BN stats)
//   3) finalize1: BN scales; w_eff = w_mr * col-scale (additive terms cancel)
//   4) GEMM2: h_pre = w_eff @ [y_in ; y_df] (+BN stats)
//   5) finalize2 ; 6) epilogue: out = a_in*y_in + d_in + gelu(a_m*h + d_m)
// GEMMs: MFMA bf16 16x16x32 hi/lo split (3 mfma), depth-4 register prefetch,
// double-buffered LDS (1 barrier/chunk). BN stats: 32-way spread atomics.
// ---------------------------------------------------------------------------

#define INV_NPIX (1.0f / 131072.0f)
#define EPS 1e-5f
#define KP 66  // LDS dword stride per k-row (64 + 2 pad: conflict-free)

typedef __attribute__((ext_vector_type(8))) short s16x8;
typedef __attribute__((ext_vector_type(4))) float f32x4;

__device__ __forceinline__ uint32_t bf16_rne(float v) {
  uint32_t x = __float_as_uint(v);
  return (x + 0x7fffu + ((x >> 16) & 1u)) >> 16;
}
// pack (hi bf16) | (lo bf16 << 16), v ~= hi + lo
__device__ __forceinline__ uint32_t pack_hl(float v) {
  uint32_t h = bf16_rne(v);
  float lo = v - __uint_as_float(h << 16);
  return h | (bf16_rne(lo) << 16);
}

__device__ __forceinline__ float4 fmin4(float4 a, float4 b) {
  return make_float4(fminf(a.x, b.x), fminf(a.y, b.y), fminf(a.z, b.z),
                     fminf(a.w, b.w));
}

// ------------------- stencil + weight prep + stats zero ---------------------
// blocks 0..4095: stencil planes. blocks 4096..4223: prep/zero.
__global__ __launch_bounds__(256) void stencil_prep_kernel(
    const float* __restrict__ x, float* __restrict__ out,
    const float* __restrict__ w_in, const float* __restrict__ w_diff,
    unsigned short* __restrict__ wInH, unsigned short* __restrict__ wInL,
    unsigned short* __restrict__ wDfH, unsigned short* __restrict__ wDfL,
    float* __restrict__ stats) {
  __shared__ float4 p4[1024];
  if (blockIdx.x >= 4096) {
    const int t = (blockIdx.x - 4096) * 256 + threadIdx.x;  // 0..32767
    if (t < 24576) stats[t] = 0.f;
    const int e = t & 16383;
    const float* w = (t < 16384) ? w_in : w_diff;
    unsigned short* aH = (t < 16384) ? wInH : wDfH;
    unsigned short* aL = (t < 16384) ? wInL : wDfL;
    const int j = e & 7, l = (e >> 3) & 63, mt = (e >> 9) & 7, kc = e >> 12;
    const int m = mt * 16 + (l & 15);
    const int k = kc * 32 + ((l >> 4) << 3) + j;
    const uint32_t p = pack_hl(w[m * 128 + k]);
    aH[e] = (unsigned short)(p & 0xffffu);
    aL[e] = (unsigned short)(p >> 16);
    return;
  }
  const size_t base4 = (size_t)blockIdx.x * 1024;  // float4 units
  float4 self[4];
#pragma unroll
  for (int i = 0; i < 4; ++i) {
    const int u = threadIdx.x + i * 256;
    self[i] = ((const float4*)x)[base4 + u];
    p4[u] = self[i];
  }
  __syncthreads();
#pragma unroll
  for (int i = 0; i < 4; ++i) {
    const int u = threadIdx.x + i * 256;
    const int h = u >> 4, wu = u & 15;
    const int row = u & ~15;
    const float4 A = self[i];
    const float4 L = p4[row | ((wu + 15) & 15)];
    const float4 R = p4[row | ((wu + 1) & 15)];
    float4 m = A;
    m = fmin4(m, L);
    m = fmin4(m, R);
    // w +/- 2 from existing vectors
    m = fmin4(m, make_float4(A.z, A.w, R.x, R.y));
    m = fmin4(m, make_float4(L.z, L.w, A.x, A.y));
    // w +/- 8, 16, 32 (units 2, 4, 8)
    m = fmin4(m, p4[row | ((wu + 2) & 15)]);
    m = fmin4(m, p4[row | ((wu + 14) & 15)]);
    m = fmin4(m, p4[row | ((wu + 4) & 15)]);
    m = fmin4(m, p4[row | ((wu + 12) & 15)]);
    m = fmin4(m, p4[row | ((wu + 8) & 15)]);
    // h +/- 2,4,8,16 and +32 (circular)
    m = fmin4(m, p4[(((h + 2) & 63) << 4) | wu]);
    m = fmin4(m, p4[(((h + 62) & 63) << 4) | wu]);
    m = fmin4(m, p4[(((h + 4) & 63) << 4) | wu]);
    m = fmin4(m, p4[(((h + 60) & 63) << 4) | wu]);
    m = fmin4(m, p4[(((h + 8) & 63) << 4) | wu]);
    m = fmin4(m, p4[(((h + 56) & 63) << 4) | wu]);
    m = fmin4(m, p4[(((h + 16) & 63) << 4) | wu]);
    m = fmin4(m, p4[(((h + 48) & 63) << 4) | wu]);
    m = fmin4(m, p4[(((h + 32) & 63) << 4) | wu]);
    float4 o;
    o.x = A.x - m.x;
    o.y = A.y - m.y;
    o.z = A.z - m.z;
    o.w = A.w - m.w;
    ((float4*)out)[base4 + u] = o;
  }
}

// --------------------------- MFMA GEMM body ---------------------------------
// out[m,n] = sum_k A[m,k]*B[k,n]; M=128, N=131072.
// B row k of batch b at (k<128 ? B0 : B1) + (b*128 + (k&127))*4096 + hw.
// 256 thr (4 waves), tile M=128 x N=64, K-chunk 32, depth-4 prefetch,
// double-buffered LDS, one barrier per chunk.
template <int K>
__device__ __forceinline__ void gemm_body(
    const unsigned short* __restrict__ AH, const unsigned short* __restrict__ AL,
    const float* __restrict__ B0, const float* __restrict__ B1,
    float* __restrict__ out, float* __restrict__ sumv,
    float* __restrict__ sumq, const int bx, uint32_t* Bs) {
  const int tid = threadIdx.x;
  const int lane = tid & 63;
  const int wave = tid >> 6;
  const int b = bx >> 6;
  const int hw0 = (bx & 63) << 6;
  const int sn4 = tid & 15;  // staging: float4 column
  const int sk = tid >> 4;   // staging: k-row (0..15), +16 second slot
  const int q = lane >> 4;
  const int ln = lane & 15;
  constexpr int NC = K / 32;

  f32x4 acc[2][4];
#pragma unroll
  for (int i = 0; i < 2; ++i)
#pragma unroll
    for (int j = 0; j < 4; ++j) acc[i][j] = (f32x4)(0.0f);

  // prologue: issue loads for chunks 0..3 (all of B0's first 128 rows slice)
  float4 ld[4][2];
#pragma unroll
  for (int c = 0; c < 4; ++c) {
#pragma unroll
    for (int s = 0; s < 2; ++s) {
      const int kr = sk + s * 16;
      ld[c][s] = *(const float4*)&B0[((size_t)b * 128 + c * 32 + kr) * 4096 +
                                     hw0 + (sn4 << 2)];
    }
  }

#pragma unroll
  for (int kc = 0; kc < NC; ++kc) {
    const int slot = kc & 3;
    const int bsel = kc & 1;
    uint32_t* buf = Bs + bsel * (32 * KP);
    // ---- pack current chunk into LDS (waits only its own loads) ----
#pragma unroll
    for (int s = 0; s < 2; ++s) {
      const int kr = sk + s * 16;
      uint2 d01, d23;
      d01.x = pack_hl(ld[slot][s].x);
      d01.y = pack_hl(ld[slot][s].y);
      d23.x = pack_hl(ld[slot][s].z);
      d23.y = pack_hl(ld[slot][s].w);
      *(uint2*)&buf[kr * KP + (sn4 << 2)] = d01;
      *(uint2*)&buf[kr * KP + (sn4 << 2) + 2] = d23;
    }
    // ---- A frags (L2-resident) -- issued BEFORE B prefetch so the mfma
    // vmcnt wait does not drain the prefetch
    s16x8 ah[2], al[2];
#pragma unroll
    for (int mt2 = 0; mt2 < 2; ++mt2) {
      const size_t off = ((size_t)((kc * 8 + wave * 2 + mt2) * 64 + lane)) << 3;
      ah[mt2] = *(const s16x8*)(AH + off);
      al[mt2] = *(const s16x8*)(AL + off);
    }
    // ---- prefetch chunk kc+4 (K=256 only: rows 128.. from B1) ----
    if (K == 256 && kc < 4) {
#pragma unroll
      for (int s = 0; s < 2; ++s) {
        const int kr = sk + s * 16;
        ld[slot][s] = *(const float4*)&B1[((size_t)b * 128 + kc * 32 + kr) *
                                              4096 + hw0 + (sn4 << 2)];
      }
    }
    __syncthreads();
    // ---- compute ----
#pragma unroll
    for (int nt = 0; nt < 4; ++nt) {
      uint32_t dj[8];
#pragma unroll
      for (int j = 0; j < 8; ++j) dj[j] = buf[(q * 8 + j) * KP + nt * 16 + ln];
      union { uint32_t u[4]; s16x8 s; } bh, bl;
#pragma unroll
      for (int jj = 0; jj < 4; ++jj) {
        bh.u[jj] = __builtin_amdgcn_perm(dj[2 * jj + 1], dj[2 * jj], 0x05040100u);
        bl.u[jj] = __builtin_amdgcn_perm(dj[2 * jj + 1], dj[2 * jj], 0x07060302u);
      }
#pragma unroll
      for (int mt2 = 0; mt2 < 2; ++mt2) {
        acc[mt2][nt] = __builtin_amdgcn_mfma_f32_16x16x32_bf16(
            ah[mt2], bh.s, acc[mt2][nt], 0, 0, 0);
        acc[mt2][nt] = __builtin_amdgcn_mfma_f32_16x16x32_bf16(
            ah[mt2], bl.s, acc[mt2][nt], 0, 0, 0);
        acc[mt2][nt] = __builtin_amdgcn_mfma_f32_16x16x32_bf16(
            al[mt2], bh.s, acc[mt2][nt], 0, 0, 0);
      }
    }
    // no trailing barrier: next pack writes the OTHER LDS buffer; its
    // previous readers finished before the barrier above.
  }

  // ---- store + per-channel stats (32-way spread atomics) ----
  const int cb = (bx & 31) * 128;
#pragma unroll
  for (int mt2 = 0; mt2 < 2; ++mt2) {
    float sa[4] = {0.f, 0.f, 0.f, 0.f};
    float sq[4] = {0.f, 0.f, 0.f, 0.f};
#pragma unroll
    for (int nt = 0; nt < 4; ++nt) {
#pragma unroll
      for (int r = 0; r < 4; ++r) {
        const float v = acc[mt2][nt][r];
        const int m = (wave * 2 + mt2) * 16 + q * 4 + r;
        out[((size_t)b * 128 + m) * 4096 + hw0 + nt * 16 + ln] = v;
        sa[r] += v;
        sq[r] += v * v;
      }
    }
#pragma unroll
    for (int off = 1; off < 16; off <<= 1) {
#pragma unroll
      for (int r = 0; r < 4; ++r) {
        sa[r] += __shfl_xor(sa[r], off);
        sq[r] += __shfl_xor(sq[r], off);
      }
    }
    if (ln == 0) {
#pragma unroll
      for (int r = 0; r < 4; ++r) {
        const int m = (wave * 2 + mt2) * 16 + q * 4 + r;
        atomicAdd(&sumv[cb + m], sa[r]);
        atomicAdd(&sumq[cb + m], sq[r]);
      }
    }
  }
}

// gemm1a + gemm1b in one dispatch (4096 blocks)
__global__ __launch_bounds__(256) void gemm1_dual(
    const unsigned short* __restrict__ AH1, const unsigned short* __restrict__ AL1,
    const float* __restrict__ X, float* __restrict__ out1,
    float* __restrict__ sv1, float* __restrict__ sq1,
    const unsigned short* __restrict__ AH2, const unsigned short* __restrict__ AL2,
    const float* __restrict__ F, float* __restrict__ out2,
    float* __restrict__ sv2, float* __restrict__ sq2) {
  __shared__ uint32_t Bs[2 * 32 * KP];
  const int bx = blockIdx.x & 2047;
  if ((blockIdx.x >> 11) == 0)
    gemm_body<128>(AH1, AL1, X, nullptr, out1, sv1, sq1, bx, Bs);
  else
    gemm_body<128>(AH2, AL2, F, nullptr, out2, sv2, sq2, bx, Bs);
}

__global__ __launch_bounds__(256) void gemm2_kernel(
    const unsigned short* __restrict__ AH, const unsigned short* __restrict__ AL,
    const float* __restrict__ B0, const float* __restrict__ B1,
    float* __restrict__ out, float* __restrict__ sv, float* __restrict__ sq) {
  __shared__ uint32_t Bs[2 * 32 * KP];
  gemm_body<256>(AH, AL, B0, B1, out, sv, sq, blockIdx.x, Bs);
}

// --------------------------- finalize kernels -------------------------------
// 128 blocks; each computes sa[256] (cheap, redundant) and packs 256 w_eff
// elements. Block 0 also writes a_in/d_in.
__global__ __launch_bounds__(256) void finalize1_kernel(
    const float* __restrict__ pSin, const float* __restrict__ pQin,
    const float* __restrict__ pSdf, const float* __restrict__ pQdf,
    const float* __restrict__ g_ibn, const float* __restrict__ be_ibn,
    const float* __restrict__ g_bn, const float* __restrict__ w_mr,
    float* __restrict__ a_in, float* __restrict__ d_in,
    unsigned short* __restrict__ wEffH, unsigned short* __restrict__ wEffL) {
  __shared__ float sa[256];
  const int t = threadIdx.x;
  if (t < 128) {
    float s = 0.f, qq = 0.f;
#pragma unroll
    for (int i = 0; i < 32; ++i) {
      s += pSin[i * 128 + t];
      qq += pQin[i * 128 + t];
    }
    const float mu = s * INV_NPIX;
    const float var = fmaxf(qq * INV_NPIX - mu * mu, 0.f);
    const float a = g_ibn[t] * rsqrtf(var + EPS);
    if (blockIdx.x == 0) {
      a_in[t] = a;
      d_in[t] = be_ibn[t] - mu * a;
    }
    sa[t] = a;
  } else {
    const int c = t - 128;
    float s = 0.f, qq = 0.f;
#pragma unroll
    for (int i = 0; i < 32; ++i) {
      s += pSdf[i * 128 + c];
      qq += pQdf[i * 128 + c];
    }
    const float mu = s * INV_NPIX;
    const float var = fmaxf(qq * INV_NPIX - mu * mu, 0.f);
    sa[t] = g_bn[c] * rsqrtf(var + EPS);
  }
  __syncthreads();
  // frag-ordered hi/lo of w_eff[m][k] = w_mr[m][k]*sa[k], Kdim=256
  const int e = blockIdx.x * 256 + t;
  const int j = e & 7, l = (e >> 3) & 63, mt = (e >> 9) & 7, kc = e >> 12;
  const int m = mt * 16 + (l & 15);
  const int k = kc * 32 + ((l >> 4) << 3) + j;
  const uint32_t p = pack_hl(w_mr[m * 256 + k] * sa[k]);
  wEffH[e] = (unsigned short)(p & 0xffffu);
  wEffL[e] = (unsigned short)(p >> 16);
}

__global__ __launch_bounds__(128) void finalize2_kernel(
    const float* __restrict__ pSh, const float* __restrict__ pQh,
    const float* __restrict__ g_mbn, const float* __restrict__ be_mbn,
    float* __restrict__ a_m, float* __restrict__ d_m) {
  const int t = threadIdx.x;
  float s = 0.f, qq = 0.f;
#pragma unroll
  for (int i = 0; i < 32; ++i) {
    s += pSh[i * 128 + t];
    qq += pQh[i * 128 + t];
  }
  const float mu = s * INV_NPIX;
  const float var = fmaxf(qq * INV_NPIX - mu * mu, 0.f);
  const float a = g_mbn[t] * rsqrtf(var + EPS);
  a_m[t] = a;
  d_m[t] = be_mbn[t] - mu * a;
}

// --------------------------- epilogue ---------------------------------------
__device__ __forceinline__ float gelu_exact(float z) {
  return 0.5f * z * (1.0f + erff(z * 0.70710678118654752f));
}

__global__ __launch_bounds__(256) void epilogue_kernel(
    const float* __restrict__ y_in, const float* __restrict__ h_pre,
    const float* __restrict__ a_in, const float* __restrict__ d_in,
    const float* __restrict__ a_m, const float* __restrict__ d_m,
    float* __restrict__ out) {
  const size_t i = (size_t)blockIdx.x * 256 + threadIdx.x;  // float4 index
  const int c = (int)((i >> 10) & 127);
  const float4 y = ((const float4*)y_in)[i];
  const float4 h = ((const float4*)h_pre)[i];
  const float ai = a_in[c], di = d_in[c], am = a_m[c], dm = d_m[c];
  float4 o;
  o.x = fmaf(ai, y.x, di) + gelu_exact(fmaf(am, h.x, dm));
  o.y = fmaf(ai, y.y, di) + gelu_exact(fmaf(am, h.y, dm));
  o.z = fmaf(ai, y.z, di) + gelu_exact(fmaf(am, h.z, dm));
  o.w = fmaf(ai, y.w, di) + gelu_exact(fmaf(am, h.w, dm));
  ((float4*)out)[i] = o;
}

// --------------------------- launch -----------------------------------------
extern "C" void kernel_launch(void* const* d_in, const int* in_sizes, int n_in,
                              void* d_out, int out_size, void* d_ws,
                              size_t ws_size, hipStream_t stream) {
  const float* x = (const float*)d_in[0];
  const float* w_diff = (const float*)d_in[1];
  const float* g_bn = (const float*)d_in[3];
  const float* w_in = (const float*)d_in[5];
  const float* g_ibn = (const float*)d_in[7];
  const float* be_ibn = (const float*)d_in[8];
  const float* w_mr = (const float*)d_in[9];
  const float* g_mbn = (const float*)d_in[11];
  const float* be_mbn = (const float*)d_in[12];
  float* out = (float*)d_out;

  const size_t NB = (size_t)16777216;  // 32*128*64*64
  float* ws = (float*)d_ws;
  float* buf0 = ws;           // fmax, then h_pre
  float* buf1 = ws + NB;      // y_in
  float* buf2 = ws + 2 * NB;  // y_diff
  float* st = ws + 3 * NB;
  // 32-way spread partial stats (each 32*128 = 4096 floats); zeroed in stencil
  float* pSin = st, *pQin = st + 4096;
  float* pSdf = st + 8192, *pQdf = st + 12288;
  float* pSh = st + 16384, *pQh = st + 20480;
  float* a_in = st + 24576, *dinc = st + 24704;
  float* a_m = st + 24832, *d_m = st + 24960;
  unsigned short* fr = (unsigned short*)(st + 25088);
  unsigned short* wInH = fr;           // 16384 each
  unsigned short* wInL = fr + 16384;
  unsigned short* wDfH = fr + 32768;
  unsigned short* wDfL = fr + 49152;
  unsigned short* wEffH = fr + 65536;  // 32768 each
  unsigned short* wEffL = fr + 98304;

  stencil_prep_kernel<<<4224, 256, 0, stream>>>(x, buf0, w_in, w_diff, wInH,
                                                wInL, wDfH, wDfL, st);
  gemm1_dual<<<4096, 256, 0, stream>>>(wInH, wInL, x, buf1, pSin, pQin, wDfH,
                                       wDfL, buf0, buf2, pSdf, pQdf);
  finalize1_kernel<<<128, 256, 0, stream>>>(pSin, pQin, pSdf, pQdf, g_ibn,
                                            be_ibn, g_bn, w_mr, a_in, dinc,
                                            wEffH, wEffL);
  gemm2_kernel<<<2048, 256, 0, stream>>>(wEffH, wEffL, buf1, buf2, buf0, pSh,
                                         pQh);
  finalize2_kernel<<<1, 128, 0, stream>>>(pSh, pQh, g_mbn, be_mbn, a_m, d_m);
  epilogue_kernel<<<16384, 256, 0, stream>>>(buf1, buf0, a_in, dinc, a_m, d_m,
                                             out);
}

// Round 5
// 271.165 us; speedup vs baseline: 4.2894x; 1.0200x over previous
//
#include <hip/hip_runtime.h>
#include <math.h>

// ---------------------------------------------------------------------------
// LSGC: B=32, C=128, H=W=64. N_pixels = 32*64*64 = 131072.
// All intermediates stored as bf16 "k-pair" dwords: d = bf16[2c] | bf16[2c+1]<<16,
// layout [b][c/2][hw] — exactly MFMA B-frag pair order, so GEMM staging is a
// raw 16B copy and B-frags are 4 strided ds_read_b32 (conflict-free).
//   1) stencil: fmax = x - min(...); emits x-pairs and fmax-pairs (+w prep)
//   2) gemm1 dual: y_in = w_in @ x ; y_df = w_diff @ fmax  (+BN stats)
//   3) finalize1: BN scales; w_eff = w_mr * col-scale (additive terms cancel)
//   4) gemm2: h = w_eff @ [y_in ; y_df] (+BN stats)
//   5) finalize2 ; 6) epilogue: out = a_in*y_in + d_in + gelu(a_m*h + d_m)
// A-side (weights) kept hi/lo split (2 mfma: ah*b + al*b) for fp32-grade w.
// ---------------------------------------------------------------------------

#define INV_NPIX (1.0f / 131072.0f)
#define EPS 1e-5f
#define KP 66  // LDS dword pitch per k2-row (64 + 2: conflict-free)

typedef __attribute__((ext_vector_type(8))) short s16x8;
typedef __attribute__((ext_vector_type(4))) float f32x4;

__device__ __forceinline__ uint32_t bf16_rne(float v) {
  uint32_t x = __float_as_uint(v);
  return (x + 0x7fffu + ((x >> 16) & 1u)) >> 16;
}
// pack (hi bf16) | (lo bf16 << 16), v ~= hi + lo   (A-side hi/lo split)
__device__ __forceinline__ uint32_t pack_hl(float v) {
  uint32_t h = bf16_rne(v);
  float lo = v - __uint_as_float(h << 16);
  return h | (bf16_rne(lo) << 16);
}
__device__ __forceinline__ float bf_lo(uint32_t d) {
  return __uint_as_float(d << 16);
}
__device__ __forceinline__ float bf_hi(uint32_t d) {
  return __uint_as_float(d & 0xffff0000u);
}
__device__ __forceinline__ float4 fmin4(float4 a, float4 b) {
  return make_float4(fminf(a.x, b.x), fminf(a.y, b.y), fminf(a.z, b.z),
                     fminf(a.w, b.w));
}

// ------------- stencil (2 planes/block) + pair-pack + prep ------------------
// blocks 0..2047: (b, cpair) planes -> x-pairs + fmax-pairs.
// blocks 2048..2175: weight frag-pack + stats zeroing.
__global__ __launch_bounds__(256) void stencil_prep_kernel(
    const float* __restrict__ x, uint32_t* __restrict__ xp,
    uint32_t* __restrict__ fp, const float* __restrict__ w_in,
    const float* __restrict__ w_diff, unsigned short* __restrict__ wInH,
    unsigned short* __restrict__ wInL, unsigned short* __restrict__ wDfH,
    unsigned short* __restrict__ wDfL, float* __restrict__ stats) {
  __shared__ float4 pA[1024];
  __shared__ float4 pB[1024];
  if (blockIdx.x >= 2048) {
    const int t = (blockIdx.x - 2048) * 256 + threadIdx.x;  // 0..32767
    if (t < 24576) stats[t] = 0.f;
    const int e = t & 16383;
    const float* w = (t < 16384) ? w_in : w_diff;
    unsigned short* aH = (t < 16384) ? wInH : wDfH;
    unsigned short* aL = (t < 16384) ? wInL : wDfL;
    const int j = e & 7, l = (e >> 3) & 63, mt = (e >> 9) & 7, kc = e >> 12;
    const int m = mt * 16 + (l & 15);
    const int k = kc * 32 + ((l >> 4) << 3) + j;
    const uint32_t p = pack_hl(w[m * 128 + k]);
    aH[e] = (unsigned short)(p & 0xffffu);
    aL[e] = (unsigned short)(p >> 16);
    return;
  }
  const int b = blockIdx.x >> 6;
  const int cp = blockIdx.x & 63;
  const float4* xa = (const float4*)x + (size_t)(b * 128 + 2 * cp) * 1024;
  const float4* xb = xa + 1024;
  float4 sA[4], sB[4];
#pragma unroll
  for (int i = 0; i < 4; ++i) {
    const int u = threadIdx.x + i * 256;
    sA[i] = xa[u];
    sB[i] = xb[u];
    pA[u] = sA[i];
    pB[u] = sB[i];
  }
  __syncthreads();
  const size_t obase = (size_t)(b * 64 + cp) * 1024;  // uint4 units
#pragma unroll
  for (int i = 0; i < 4; ++i) {
    const int u = threadIdx.x + i * 256;
    const int h = u >> 4, wu = u & 15;
    const int row = u & ~15;
    float4 mA, mB;
    {
      const float4 A = sA[i];
      const float4 L = pA[row | ((wu + 15) & 15)];
      const float4 R = pA[row | ((wu + 1) & 15)];
      float4 m = fmin4(A, fmin4(L, R));
      m = fmin4(m, make_float4(A.z, A.w, R.x, R.y));
      m = fmin4(m, make_float4(L.z, L.w, A.x, A.y));
      m = fmin4(m, pA[row | ((wu + 2) & 15)]);
      m = fmin4(m, pA[row | ((wu + 14) & 15)]);
      m = fmin4(m, pA[row | ((wu + 4) & 15)]);
      m = fmin4(m, pA[row | ((wu + 12) & 15)]);
      m = fmin4(m, pA[row | ((wu + 8) & 15)]);
      m = fmin4(m, pA[(((h + 2) & 63) << 4) | wu]);
      m = fmin4(m, pA[(((h + 62) & 63) << 4) | wu]);
      m = fmin4(m, pA[(((h + 4) & 63) << 4) | wu]);
      m = fmin4(m, pA[(((h + 60) & 63) << 4) | wu]);
      m = fmin4(m, pA[(((h + 8) & 63) << 4) | wu]);
      m = fmin4(m, pA[(((h + 56) & 63) << 4) | wu]);
      m = fmin4(m, pA[(((h + 16) & 63) << 4) | wu]);
      m = fmin4(m, pA[(((h + 48) & 63) << 4) | wu]);
      m = fmin4(m, pA[(((h + 32) & 63) << 4) | wu]);
      mA = m;
    }
    {
      const float4 A = sB[i];
      const float4 L = pB[row | ((wu + 15) & 15)];
      const float4 R = pB[row | ((wu + 1) & 15)];
      float4 m = fmin4(A, fmin4(L, R));
      m = fmin4(m, make_float4(A.z, A.w, R.x, R.y));
      m = fmin4(m, make_float4(L.z, L.w, A.x, A.y));
      m = fmin4(m, pB[row | ((wu + 2) & 15)]);
      m = fmin4(m, pB[row | ((wu + 14) & 15)]);
      m = fmin4(m, pB[row | ((wu + 4) & 15)]);
      m = fmin4(m, pB[row | ((wu + 12) & 15)]);
      m = fmin4(m, pB[row | ((wu + 8) & 15)]);
      m = fmin4(m, pB[(((h + 2) & 63) << 4) | wu]);
      m = fmin4(m, pB[(((h + 62) & 63) << 4) | wu]);
      m = fmin4(m, pB[(((h + 4) & 63) << 4) | wu]);
      m = fmin4(m, pB[(((h + 60) & 63) << 4) | wu]);
      m = fmin4(m, pB[(((h + 8) & 63) << 4) | wu]);
      m = fmin4(m, pB[(((h + 56) & 63) << 4) | wu]);
      m = fmin4(m, pB[(((h + 16) & 63) << 4) | wu]);
      m = fmin4(m, pB[(((h + 48) & 63) << 4) | wu]);
      m = fmin4(m, pB[(((h + 32) & 63) << 4) | wu]);
      mB = m;
    }
    uint4 px, pf;
    px.x = bf16_rne(sA[i].x) | (bf16_rne(sB[i].x) << 16);
    px.y = bf16_rne(sA[i].y) | (bf16_rne(sB[i].y) << 16);
    px.z = bf16_rne(sA[i].z) | (bf16_rne(sB[i].z) << 16);
    px.w = bf16_rne(sA[i].w) | (bf16_rne(sB[i].w) << 16);
    pf.x = bf16_rne(sA[i].x - mA.x) | (bf16_rne(sB[i].x - mB.x) << 16);
    pf.y = bf16_rne(sA[i].y - mA.y) | (bf16_rne(sB[i].y - mB.y) << 16);
    pf.z = bf16_rne(sA[i].z - mA.z) | (bf16_rne(sB[i].z - mB.z) << 16);
    pf.w = bf16_rne(sA[i].w - mA.w) | (bf16_rne(sB[i].w - mB.w) << 16);
    ((uint4*)xp)[obase + u] = px;
    ((uint4*)fp)[obase + u] = pf;
  }
}

// --------------------------- MFMA GEMM body ---------------------------------
// out[m,n] = sum_k A[m,k]*B[k,n]; M=128, N=131072. B in bf16-pair dwords
// [b][k2][hw]; k2<64 from B0, else B1. Tile M=128 x N=64, k-chunk 32 (16 k2
// rows), depth-4 register prefetch, double-buffered LDS, 1 barrier/chunk.
template <int NC>  // 4 (K=128) or 8 (K=256)
__device__ __forceinline__ void gemm_body(
    const unsigned short* __restrict__ AH, const unsigned short* __restrict__ AL,
    const uint32_t* __restrict__ B0, const uint32_t* __restrict__ B1,
    uint32_t* __restrict__ outp, float* __restrict__ sumv,
    float* __restrict__ sumq, const int bx, uint32_t* Bs) {
  const int tid = threadIdx.x;
  const int lane = tid & 63;
  const int wave = tid >> 6;
  const int b = bx >> 6;
  const int hw0 = (bx & 63) << 6;
  const int sk2 = tid >> 4;         // staging k2-row 0..15
  const int sn4 = (tid & 15) << 2;  // staging dword4 column
  const int q = lane >> 4;
  const int ln = lane & 15;

  f32x4 acc[2][4];
#pragma unroll
  for (int i = 0; i < 2; ++i)
#pragma unroll
    for (int j = 0; j < 4; ++j) acc[i][j] = (f32x4)(0.0f);

  // prologue: chunks 0..3 (k2 rows 0..63 of B0)
  uint4 ld[4];
#pragma unroll
  for (int c = 0; c < 4; ++c)
    ld[c] = *(const uint4*)&B0[((size_t)(b * 64 + c * 16 + sk2)) * 4096 + hw0 +
                               sn4];

#pragma unroll
  for (int kc = 0; kc < NC; ++kc) {
    const int slot = kc & 3;
    uint32_t* buf = Bs + (kc & 1) * (16 * KP);
    *(uint4*)&buf[sk2 * KP + sn4] = ld[slot];
    // A frags (L2-resident), issued before prefetch
    s16x8 ah[2], al[2];
#pragma unroll
    for (int mt2 = 0; mt2 < 2; ++mt2) {
      const size_t off = ((size_t)((kc * 8 + wave * 2 + mt2) * 64 + lane)) << 3;
      ah[mt2] = *(const s16x8*)(AH + off);
      al[mt2] = *(const s16x8*)(AL + off);
    }
    if (NC == 8 && kc < 4) {
      ld[slot] = *(const uint4*)&B1[((size_t)(b * 64 + kc * 16 + sk2)) * 4096 +
                                    hw0 + sn4];
    }
    __syncthreads();
#pragma unroll
    for (int nt = 0; nt < 4; ++nt) {
      union { uint32_t u[4]; s16x8 s; } bb;
#pragma unroll
      for (int j = 0; j < 4; ++j)
        bb.u[j] = buf[(q * 4 + j) * KP + nt * 16 + ln];
#pragma unroll
      for (int mt2 = 0; mt2 < 2; ++mt2) {
        acc[mt2][nt] = __builtin_amdgcn_mfma_f32_16x16x32_bf16(
            ah[mt2], bb.s, acc[mt2][nt], 0, 0, 0);
        acc[mt2][nt] = __builtin_amdgcn_mfma_f32_16x16x32_bf16(
            al[mt2], bb.s, acc[mt2][nt], 0, 0, 0);
      }
    }
  }

  // ---- store bf16-pairs + per-channel stats (32-way spread atomics) ----
  const int cb = (bx & 31) * 128;
#pragma unroll
  for (int mt2 = 0; mt2 < 2; ++mt2) {
    float sa[4] = {0.f, 0.f, 0.f, 0.f};
    float sq[4] = {0.f, 0.f, 0.f, 0.f};
#pragma unroll
    for (int nt = 0; nt < 4; ++nt) {
#pragma unroll
      for (int rp = 0; rp < 2; ++rp) {
        const float v0 = acc[mt2][nt][2 * rp];
        const float v1 = acc[mt2][nt][2 * rp + 1];
        const int m2 = (wave * 2 + mt2) * 8 + q * 2 + rp;
        outp[((size_t)(b * 64 + m2)) * 4096 + hw0 + nt * 16 + ln] =
            bf16_rne(v0) | (bf16_rne(v1) << 16);
        sa[2 * rp] += v0;
        sq[2 * rp] += v0 * v0;
        sa[2 * rp + 1] += v1;
        sq[2 * rp + 1] += v1 * v1;
      }
    }
#pragma unroll
    for (int off = 1; off < 16; off <<= 1) {
#pragma unroll
      for (int r = 0; r < 4; ++r) {
        sa[r] += __shfl_xor(sa[r], off);
        sq[r] += __shfl_xor(sq[r], off);
      }
    }
    if (ln == 0) {
#pragma unroll
      for (int r = 0; r < 4; ++r) {
        const int m = (wave * 2 + mt2) * 16 + q * 4 + r;
        atomicAdd(&sumv[cb + m], sa[r]);
        atomicAdd(&sumq[cb + m], sq[r]);
      }
    }
  }
}

// gemm1a + gemm1b in one dispatch (4096 blocks)
__global__ __launch_bounds__(256) void gemm1_dual(
    const unsigned short* __restrict__ AH1, const unsigned short* __restrict__ AL1,
    const uint32_t* __restrict__ XP, uint32_t* __restrict__ out1,
    float* __restrict__ sv1, float* __restrict__ sq1,
    const unsigned short* __restrict__ AH2, const unsigned short* __restrict__ AL2,
    const uint32_t* __restrict__ FP, uint32_t* __restrict__ out2,
    float* __restrict__ sv2, float* __restrict__ sq2) {
  __shared__ uint32_t Bs[2 * 16 * KP];
  const int bx = blockIdx.x & 2047;
  if ((blockIdx.x >> 11) == 0)
    gemm_body<4>(AH1, AL1, XP, nullptr, out1, sv1, sq1, bx, Bs);
  else
    gemm_body<4>(AH2, AL2, FP, nullptr, out2, sv2, sq2, bx, Bs);
}

__global__ __launch_bounds__(256) void gemm2_kernel(
    const unsigned short* __restrict__ AH, const unsigned short* __restrict__ AL,
    const uint32_t* __restrict__ B0, const uint32_t* __restrict__ B1,
    uint32_t* __restrict__ outp, float* __restrict__ sv,
    float* __restrict__ sq) {
  __shared__ uint32_t Bs[2 * 16 * KP];
  gemm_body<8>(AH, AL, B0, B1, outp, sv, sq, blockIdx.x, Bs);
}

// --------------------------- finalize kernels -------------------------------
__global__ __launch_bounds__(256) void finalize1_kernel(
    const float* __restrict__ pSin, const float* __restrict__ pQin,
    const float* __restrict__ pSdf, const float* __restrict__ pQdf,
    const float* __restrict__ g_ibn, const float* __restrict__ be_ibn,
    const float* __restrict__ g_bn, const float* __restrict__ w_mr,
    float* __restrict__ a_in, float* __restrict__ d_in,
    unsigned short* __restrict__ wEffH, unsigned short* __restrict__ wEffL) {
  __shared__ float sa[256];
  const int t = threadIdx.x;
  if (t < 128) {
    float s = 0.f, qq = 0.f;
#pragma unroll
    for (int i = 0; i < 32; ++i) {
      s += pSin[i * 128 + t];
      qq += pQin[i * 128 + t];
    }
    const float mu = s * INV_NPIX;
    const float var = fmaxf(qq * INV_NPIX - mu * mu, 0.f);
    const float a = g_ibn[t] * rsqrtf(var + EPS);
    if (blockIdx.x == 0) {
      a_in[t] = a;
      d_in[t] = be_ibn[t] - mu * a;
    }
    sa[t] = a;
  } else {
    const int c = t - 128;
    float s = 0.f, qq = 0.f;
#pragma unroll
    for (int i = 0; i < 32; ++i) {
      s += pSdf[i * 128 + c];
      qq += pQdf[i * 128 + c];
    }
    const float mu = s * INV_NPIX;
    const float var = fmaxf(qq * INV_NPIX - mu * mu, 0.f);
    sa[t] = g_bn[c] * rsqrtf(var + EPS);
  }
  __syncthreads();
  const int e = blockIdx.x * 256 + t;
  const int j = e & 7, l = (e >> 3) & 63, mt = (e >> 9) & 7, kc = e >> 12;
  const int m = mt * 16 + (l & 15);
  const int k = kc * 32 + ((l >> 4) << 3) + j;
  const uint32_t p = pack_hl(w_mr[m * 256 + k] * sa[k]);
  wEffH[e] = (unsigned short)(p & 0xffffu);
  wEffL[e] = (unsigned short)(p >> 16);
}

__global__ __launch_bounds__(128) void finalize2_kernel(
    const float* __restrict__ pSh, const float* __restrict__ pQh,
    const float* __restrict__ g_mbn, const float* __restrict__ be_mbn,
    float* __restrict__ a_m, float* __restrict__ d_m) {
  const int t = threadIdx.x;
  float s = 0.f, qq = 0.f;
#pragma unroll
  for (int i = 0; i < 32; ++i) {
    s += pSh[i * 128 + t];
    qq += pQh[i * 128 + t];
  }
  const float mu = s * INV_NPIX;
  const float var = fmaxf(qq * INV_NPIX - mu * mu, 0.f);
  const float a = g_mbn[t] * rsqrtf(var + EPS);
  a_m[t] = a;
  d_m[t] = be_mbn[t] - mu * a;
}

// --------------------------- epilogue ---------------------------------------
__device__ __forceinline__ float gelu_exact(float z) {
  return 0.5f * z * (1.0f + erff(z * 0.70710678118654752f));
}

__global__ __launch_bounds__(256) void epilogue_kernel(
    const uint32_t* __restrict__ yp, const uint32_t* __restrict__ hp,
    const float* __restrict__ a_in, const float* __restrict__ d_in,
    const float* __restrict__ a_m, const float* __restrict__ d_m,
    float* __restrict__ out) {
  const size_t i = (size_t)blockIdx.x * 256 + threadIdx.x;  // uint4 index
  const int cp = (int)((i >> 10) & 63);
  const int b = (int)(i >> 16);
  const int c0 = 2 * cp, c1 = 2 * cp + 1;
  const uint4 yv = ((const uint4*)yp)[i];
  const uint4 hv = ((const uint4*)hp)[i];
  const float a0 = a_in[c0], d0 = d_in[c0], m0 = a_m[c0], e0 = d_m[c0];
  const float a1 = a_in[c1], d1 = d_in[c1], m1 = a_m[c1], e1 = d_m[c1];
  float4 o0, o1;
  o0.x = fmaf(a0, bf_lo(yv.x), d0) + gelu_exact(fmaf(m0, bf_lo(hv.x), e0));
  o0.y = fmaf(a0, bf_lo(yv.y), d0) + gelu_exact(fmaf(m0, bf_lo(hv.y), e0));
  o0.z = fmaf(a0, bf_lo(yv.z), d0) + gelu_exact(fmaf(m0, bf_lo(hv.z), e0));
  o0.w = fmaf(a0, bf_lo(yv.w), d0) + gelu_exact(fmaf(m0, bf_lo(hv.w), e0));
  o1.x = fmaf(a1, bf_hi(yv.x), d1) + gelu_exact(fmaf(m1, bf_hi(hv.x), e1));
  o1.y = fmaf(a1, bf_hi(yv.y), d1) + gelu_exact(fmaf(m1, bf_hi(hv.y), e1));
  o1.z = fmaf(a1, bf_hi(yv.z), d1) + gelu_exact(fmaf(m1, bf_hi(hv.z), e1));
  o1.w = fmaf(a1, bf_hi(yv.w), d1) + gelu_exact(fmaf(m1, bf_hi(hv.w), e1));
  const size_t u = i & 1023;  // float4 col within row
  ((float4*)out)[(size_t)(b * 128 + c0) * 1024 + u] = o0;
  ((float4*)out)[(size_t)(b * 128 + c1) * 1024 + u] = o1;
}

// --------------------------- launch -----------------------------------------
extern "C" void kernel_launch(void* const* d_in, const int* in_sizes, int n_in,
                              void* d_out, int out_size, void* d_ws,
                              size_t ws_size, hipStream_t stream) {
  const float* x = (const float*)d_in[0];
  const float* w_diff = (const float*)d_in[1];
  const float* g_bn = (const float*)d_in[3];
  const float* w_in = (const float*)d_in[5];
  const float* g_ibn = (const float*)d_in[7];
  const float* be_ibn = (const float*)d_in[8];
  const float* w_mr = (const float*)d_in[9];
  const float* g_mbn = (const float*)d_in[11];
  const float* be_mbn = (const float*)d_in[12];
  float* out = (float*)d_out;

  const size_t PD = (size_t)8388608;  // 32*64*4096 pair-dwords per tensor
  uint32_t* ws = (uint32_t*)d_ws;
  uint32_t* xp = ws;             // x bf16-pairs
  uint32_t* fpx = ws + PD;       // fmax bf16-pairs
  uint32_t* ypIn = ws + 2 * PD;  // y_in pairs
  uint32_t* ypDf = ws + 3 * PD;  // y_df pairs
  uint32_t* hp = ws + 4 * PD;    // h pairs
  float* st = (float*)(ws + 5 * PD);
  float* pSin = st, *pQin = st + 4096;
  float* pSdf = st + 8192, *pQdf = st + 12288;
  float* pSh = st + 16384, *pQh = st + 20480;
  float* a_in = st + 24576, *dinc = st + 24704;
  float* a_m = st + 24832, *d_m = st + 24960;
  unsigned short* fr = (unsigned short*)(st + 25088);
  unsigned short* wInH = fr;           // 16384 each
  unsigned short* wInL = fr + 16384;
  unsigned short* wDfH = fr + 32768;
  unsigned short* wDfL = fr + 49152;
  unsigned short* wEffH = fr + 65536;  // 32768 each
  unsigned short* wEffL = fr + 98304;

  stencil_prep_kernel<<<2176, 256, 0, stream>>>(x, xp, fpx, w_in, w_diff,
                                                wInH, wInL, wDfH, wDfL, st);
  gemm1_dual<<<4096, 256, 0, stream>>>(wInH, wInL, xp, ypIn, pSin, pQin, wDfH,
                                       wDfL, fpx, ypDf, pSdf, pQdf);
  finalize1_kernel<<<128, 256, 0, stream>>>(pSin, pQin, pSdf, pQdf, g_ibn,
                                            be_ibn, g_bn, w_mr, a_in, dinc,
                                            wEffH, wEffL);
  gemm2_kernel<<<2048, 256, 0, stream>>>(wEffH, wEffL, ypIn, ypDf, hp, pSh,
                                         pQh);
  finalize2_kernel<<<1, 128, 0, stream>>>(pSh, pQh, g_mbn, be_mbn, a_m, d_m);
  epilogue_kernel<<<8192, 256, 0, stream>>>(ypIn, hp, a_in, dinc, a_m, d_m,
                                            out);
}